// Round 6
// baseline (906.515 us; speedup 1.0000x reference)
//
#include <hip/hip_runtime.h>
#include <hip/hip_bf16.h>

#define DIM 2048
#define NH 16
#define KVH 4
#define HD 128
#define BATCH 2
#define SEQ 2048
#define MTOT (BATCH*SEQ)
#define SCALE 0.08838834764831845f

using f32x4 = __attribute__((ext_vector_type(4))) float;
using s16x4 = __attribute__((ext_vector_type(4))) short;
using s16x8 = __attribute__((ext_vector_type(8))) short;
using bf16x8 = __attribute__((ext_vector_type(8))) __bf16;

__device__ inline short f2bf(float x) { __bf16 h = (__bf16)x; return __builtin_bit_cast(short, h); }
__device__ inline float bf2f(short s) { return (float)__builtin_bit_cast(__bf16, s); }

// Load an 8-elem MFMA fragment: 4 elems at p, 4 at p+16 (uniform enumeration everywhere).
__device__ inline bf16x8 ld_frag(const short* p) {
  s16x4 lo = *(const s16x4*)p;
  s16x4 hi = *(const s16x4*)(p + 16);
  s16x8 f = __builtin_shufflevector(lo, hi, 0, 1, 2, 3, 4, 5, 6, 7);
  return __builtin_bit_cast(bf16x8, f);
}

// Pack two f32x4 into a bf16x8 fragment (slots 0-3 = a, 4-7 = b).
__device__ inline bf16x8 pack_p(f32x4 a, f32x4 b) {
  bf16x8 o;
  o[0] = (__bf16)a[0]; o[1] = (__bf16)a[1]; o[2] = (__bf16)a[2]; o[3] = (__bf16)a[3];
  o[4] = (__bf16)b[0]; o[5] = (__bf16)b[1]; o[6] = (__bf16)b[2]; o[7] = (__bf16)b[3];
  return o;
}

// ---------------- prep kernels ----------------

__global__ void k_rope_table(float* __restrict__ tab) {
  int n = blockIdx.x, i = threadIdx.x;  // i in [0,64)
  float inv = expf(-(2.f * i / (float)HD) * logf(10000.f));
  float a = (float)n * inv;
  tab[n * HD + i] = cosf(a);
  tab[n * HD + 64 + i] = sinf(a);
}

__global__ void k_cvt_bf16(const float* __restrict__ in, short* __restrict__ out, int n4) {
  int i = blockIdx.x * 256 + threadIdx.x;
  if (i >= n4) return;
  f32x4 v = *(const f32x4*)(in + (size_t)i * 4);
  s16x4 o;
  o[0] = f2bf(v[0]); o[1] = f2bf(v[1]); o[2] = f2bf(v[2]); o[3] = f2bf(v[3]);
  *(s16x4*)(out + (size_t)i * 4) = o;
}

// W f32 [K][N] -> WT bf16 [N][K]
__global__ __launch_bounds__(256) void k_transpose(const float* __restrict__ W, short* __restrict__ WT,
                                                   int K, int N) {
  __shared__ float t[32][33];
  int n0 = blockIdx.x * 32, k0 = blockIdx.y * 32;
  int tx = threadIdx.x & 31, ty = threadIdx.x >> 5;
#pragma unroll
  for (int i = 0; i < 4; i++) t[ty + i * 8][tx] = W[(size_t)(k0 + ty + i * 8) * N + n0 + tx];
  __syncthreads();
#pragma unroll
  for (int i = 0; i < 4; i++) WT[(size_t)(n0 + ty + i * 8) * K + k0 + tx] = f2bf(t[tx][ty + i * 8]);
}

// V bf16 [.][SEQ][HD] -> [.][HD][SEQ], 64x64 tiles
__global__ __launch_bounds__(256) void k_transpose_v(const short* __restrict__ v_r, short* __restrict__ v_t) {
  __shared__ short t[64][70];
  const int z = blockIdx.z;
  const int s0 = blockIdx.x * 64, d0 = blockIdx.y * 64;
  const long ibase = ((long)z * SEQ + s0) * HD + d0;
  const long obase = ((long)z * HD + d0) * SEQ + s0;
  const int tid = threadIdx.x;
#pragma unroll
  for (int c = 0; c < 4; c++) {
    int chunk = tid + c * 256;              // 0..1023
    int row = chunk >> 4, col4 = (chunk & 15) * 4;
    *(s16x4*)&t[row][col4] = *(const s16x4*)(v_r + ibase + (long)row * HD + col4);
  }
  __syncthreads();
#pragma unroll
  for (int c = 0; c < 4; c++) {
    int chunk = tid + c * 256;
    int row = chunk >> 4, col4 = (chunk & 15) * 4; // row: hd idx, col4: seq chunk
    s16x4 o;
    o[0] = t[col4 + 0][row]; o[1] = t[col4 + 1][row];
    o[2] = t[col4 + 2][row]; o[3] = t[col4 + 3][row];
    *(s16x4*)(v_t + obase + (long)row * SEQ + col4) = o;
  }
}

// ---------------- GEMM: C = A @ BT^T (m97 structure: 128x128 tile, BK=64) ----------------
// A [M][K] bf16 rm, BT [N][K] bf16 rm.
// MODE 0: C fp32 [M][N].  MODE 1: C bf16 permuted to [B][HH][SEQ][HD].
template <int MODE, int HH>
__device__ inline void gemm_bt_body(const short* __restrict__ A, const short* __restrict__ BT,
                                    void* __restrict__ C, int M, int N, int K) {
  __shared__ short As[128 * 64];
  __shared__ short Bs[128 * 64];
  const int tid = threadIdx.x;
  const int wid = tid >> 6, lane = tid & 63;
  const int m0 = blockIdx.y * 128, n0 = blockIdx.x * 128;
  const int wr = wid >> 1, wc = wid & 1;
  const int l15 = lane & 15, g4 = (lane >> 4) * 4;
  const int lrow = lane >> 3;         // 0..7
  const int lcol = (lane & 7) * 8;    // 0..56
  f32x4 acc[4][4] = {};

  for (int kt = 0; kt < K; kt += 64) {
    __syncthreads();
#pragma unroll
    for (int c = 0; c < 4; c++) {
      int r0 = wid * 8 + c * 32;
      const short* gp = A + (long)(m0 + r0 + lrow) * K + kt + lcol;
      __builtin_amdgcn_global_load_lds((const __attribute__((address_space(1))) void*)gp,
                                       (__attribute__((address_space(3))) void*)&As[r0 * 64], 16, 0, 0);
      const short* gq = BT + (long)(n0 + r0 + lrow) * K + kt + lcol;
      __builtin_amdgcn_global_load_lds((const __attribute__((address_space(1))) void*)gq,
                                       (__attribute__((address_space(3))) void*)&Bs[r0 * 64], 16, 0, 0);
    }
    __syncthreads();
#pragma unroll
    for (int ki = 0; ki < 2; ki++) {
      bf16x8 av[4];
#pragma unroll
      for (int mt = 0; mt < 4; mt++) av[mt] = ld_frag(&As[(wr * 64 + mt * 16 + l15) * 64 + ki * 32 + g4]);
#pragma unroll
      for (int nt = 0; nt < 4; nt++) {
        bf16x8 bv = ld_frag(&Bs[(wc * 64 + nt * 16 + l15) * 64 + ki * 32 + g4]);
#pragma unroll
        for (int mt = 0; mt < 4; mt++)
          acc[mt][nt] = __builtin_amdgcn_mfma_f32_16x16x32_bf16(av[mt], bv, acc[mt][nt], 0, 0, 0);
      }
    }
  }

#pragma unroll
  for (int mt = 0; mt < 4; mt++) {
#pragma unroll
    for (int nt = 0; nt < 4; nt++) {
      int row = m0 + wr * 64 + mt * 16 + g4;
      int col = n0 + wc * 64 + nt * 16 + l15;
#pragma unroll
      for (int r = 0; r < 4; r++) {
        float v = acc[mt][nt][r];
        if (MODE == 0) {
          ((float*)C)[(long)(row + r) * N + col] = v;
        } else {
          int rg = row + r;
          int b = rg >> 11, n = rg & (SEQ - 1);
          int h = col >> 7, hd = col & (HD - 1);
          ((short*)C)[(((long)(b * HH + h)) * SEQ + n) * HD + hd] = f2bf(v);
        }
      }
    }
  }
}

__global__ __launch_bounds__(256) void k_gemm_q(const short* __restrict__ A, const short* __restrict__ BT,
                                                short* __restrict__ C, int M, int N, int K) {
  gemm_bt_body<1, NH>(A, BT, (void*)C, M, N, K);
}
__global__ __launch_bounds__(256) void k_gemm_kv(const short* __restrict__ A,
                                                 const short* __restrict__ BT0, const short* __restrict__ BT1,
                                                 short* __restrict__ C0, short* __restrict__ C1,
                                                 int M, int N, int K) {
  const short* BT = blockIdx.z ? BT1 : BT0;
  short* C = blockIdx.z ? C1 : C0;
  gemm_bt_body<1, KVH>(A, BT, (void*)C, M, N, K);
}
__global__ __launch_bounds__(256) void k_gemm_o(const short* __restrict__ A, const short* __restrict__ BT,
                                                float* __restrict__ C, int M, int N, int K) {
  gemm_bt_body<0, 0>(A, BT, (void*)C, M, N, K);
}

// ---------------- RoPE in-place on [.][heads][SEQ][HD] bf16, optional scale fold ----------------
__global__ void k_rope(short* __restrict__ t, const float* __restrict__ tab, int total, float scale) {
  int idx = blockIdx.x * 256 + threadIdx.x;
  if (idx >= total) return;
  int i = idx & 63;
  int n = (idx >> 6) & (SEQ - 1);
  long base = (long)(idx >> 6) * HD;
  float c = tab[n * HD + i], s = tab[n * HD + 64 + i];
  float x1 = bf2f(t[base + i]), x2 = bf2f(t[base + 64 + i]);
  t[base + i] = f2bf((x1 * c - x2 * s) * scale);
  t[base + 64 + i] = f2bf((x2 * c + x1 * s) * scale);
}

// ---------------- flash attention (swapped QK^T: S = [kv regs][q lanes]) ----------------
// q_r [B][NH][SEQ][HD] (pre-scaled), k_r [B][KVH][SEQ][HD], v_t [B][KVH][HD][SEQ] bf16
// out [B*SEQ][NH*HD] bf16
__global__ __launch_bounds__(256, 4) void k_attn(const short* __restrict__ q_r, const short* __restrict__ k_r,
                                                 const short* __restrict__ v_t, short* __restrict__ attn_out) {
  __shared__ short Kl[64 * 136];      // [kv 64][hd 128 pad 136]
  __shared__ short Vt[128 * 68];      // [hd 128][kv 64 pad 68]
  const int tid = threadIdx.x, wid = tid >> 6, lane = tid & 63;
  const int l15 = lane & 15, g4 = (lane >> 4) * 4;
  const int qt = (int)(gridDim.x - 1) - blockIdx.x;  // heavy blocks first
  const int bh = blockIdx.y;
  const int b = bh >> 4, h = bh & 15, kvh = h >> 2;
  const int q0 = qt * 64;

  // Q fragment: lane l15 holds q-row (q0 + wid*16 + l15)
  const long qbase = (((long)(b * NH + h)) * SEQ + q0 + wid * 16) * HD;
  bf16x8 aq[4];
#pragma unroll
  for (int kt = 0; kt < 4; kt++) aq[kt] = ld_frag(q_r + qbase + (long)l15 * HD + kt * 32 + g4);

  f32x4 acc[8] = {};
  float m_ = -1e30f, l_ = 0.f;        // per lane: stats for q = q0+wid*16+l15
  const long kvbase = ((long)(b * KVH + kvh)) * SEQ * HD;   // k_r head base
  const long vtbase = ((long)(b * KVH + kvh)) * HD * SEQ;   // v_t head base
  const int nkt = qt + 1;
  const int qg = q0 + wid * 16 + l15;

  // T14 async-stage: tile t+1 global->reg issued under tile t compute
  s16x8 kreg[4], vreg[4];
#pragma unroll
  for (int c = 0; c < 4; c++) {
    int chunk = tid + c * 256;
    int kr = chunk >> 4, kc = (chunk & 15) * 8;
    kreg[c] = *(const s16x8*)(k_r + kvbase + (long)kr * HD + kc);
    int vr = chunk >> 3, vc = (chunk & 7) * 8;
    vreg[c] = *(const s16x8*)(v_t + vtbase + (long)vr * SEQ + vc);
  }

  for (int t64 = 0; t64 < nkt; t64++) {
    __syncthreads();  // previous-iteration LDS reads done
#pragma unroll
    for (int c = 0; c < 4; c++) {
      int chunk = tid + c * 256;
      int kr = chunk >> 4, kc = (chunk & 15) * 8;
      *(s16x8*)&Kl[kr * 136 + kc] = kreg[c];
      int vr = chunk >> 3, vc = (chunk & 7) * 8;
      *(s16x8*)&Vt[vr * 68 + vc] = vreg[c];
    }
    __syncthreads();

    if (t64 + 1 < nkt) {
      const int kv0n = (t64 + 1) * 64;
#pragma unroll
      for (int c = 0; c < 4; c++) {
        int chunk = tid + c * 256;
        int kr = chunk >> 4, kc = (chunk & 15) * 8;
        kreg[c] = *(const s16x8*)(k_r + kvbase + (long)(kv0n + kr) * HD + kc);
        int vr = chunk >> 3, vc = (chunk & 7) * 8;
        vreg[c] = *(const s16x8*)(v_t + vtbase + (long)vr * SEQ + kv0n + vc);
      }
    }

    const int kv0 = t64 * 64;
    // S = K @ Q^T: s[nt][r] = S[kv = kv0+nt*16+g4+r][q = qg]  (A=K so kv lands in regs)
    f32x4 s[4] = {};
#pragma unroll
    for (int nt = 0; nt < 4; nt++) {
#pragma unroll
      for (int kt = 0; kt < 4; kt++) {
        bf16x8 bk = ld_frag(&Kl[(nt * 16 + l15) * 136 + kt * 32 + g4]);
        s[nt] = __builtin_amdgcn_mfma_f32_16x16x32_bf16(bk, aq[kt], s[nt], 0, 0, 0);
      }
    }

    // causal mask: kv > q -> -inf
#pragma unroll
    for (int nt = 0; nt < 4; nt++) {
      int kvb = kv0 + nt * 16 + g4;
#pragma unroll
      for (int r = 0; r < 4; r++)
        s[nt][r] = (kvb + r > qg) ? -1e30f : s[nt][r];
    }

    // online softmax, in-register over 16 kv values + 2 cross-hi shfls
    float tm = -1e30f;
#pragma unroll
    for (int nt = 0; nt < 4; nt++) {
      float a = fmaxf(s[nt][0], s[nt][1]), bmx = fmaxf(s[nt][2], s[nt][3]);
      tm = fmaxf(tm, fmaxf(a, bmx));
    }
    tm = fmaxf(tm, __shfl_xor(tm, 16));
    tm = fmaxf(tm, __shfl_xor(tm, 32));
    float mn = fmaxf(m_, tm);
    float corr = __expf(m_ - mn);
    m_ = mn;
    float rs = 0.f;
#pragma unroll
    for (int nt = 0; nt < 4; nt++)
#pragma unroll
      for (int r = 0; r < 4; r++) {
        float p = __expf(s[nt][r] - mn);
        s[nt][r] = p;
        rs += p;
      }
    rs += __shfl_xor(rs, 16);
    rs += __shfl_xor(rs, 32);
    l_ = l_ * corr + rs;

    // corr to reg-space (acc reg r holds q = q0+wid*16+g4+r; that q's stats sit in lane g4+r)
    float corr_r[4];
#pragma unroll
    for (int r = 0; r < 4; r++) corr_r[r] = __shfl(corr, g4 + r);
#pragma unroll
    for (int dt = 0; dt < 8; dt++)
#pragma unroll
      for (int r = 0; r < 4; r++) acc[dt][r] *= corr_r[r];

    // P fragments ARE the exp'd S regs (A-frag slot j = kv hi*4+j / 16+hi*4+j)
    bf16x8 pa0 = pack_p(s[0], s[1]);
    bf16x8 pa1 = pack_p(s[2], s[3]);

    // O += P @ V
#pragma unroll
    for (int dt = 0; dt < 8; dt++) {
      bf16x8 bv0 = ld_frag(&Vt[(dt * 16 + l15) * 68 + g4]);
      acc[dt] = __builtin_amdgcn_mfma_f32_16x16x32_bf16(pa0, bv0, acc[dt], 0, 0, 0);
      bf16x8 bv1 = ld_frag(&Vt[(dt * 16 + l15) * 68 + 32 + g4]);
      acc[dt] = __builtin_amdgcn_mfma_f32_16x16x32_bf16(pa1, bv1, acc[dt], 0, 0, 0);
    }
  }

  float inv = 1.f / l_;
  float inv_r[4];
#pragma unroll
  for (int r = 0; r < 4; r++) inv_r[r] = __shfl(inv, g4 + r);

  const long obase = ((long)(b * SEQ + q0 + wid * 16 + g4)) * (NH * HD) + (long)h * HD;
#pragma unroll
  for (int r = 0; r < 4; r++) {
#pragma unroll
    for (int dt = 0; dt < 8; dt++)
      attn_out[obase + (long)r * (NH * HD) + dt * 16 + l15] = f2bf(acc[dt][r] * inv_r[r]);
  }
}

// ---------------- launch ----------------
extern "C" void kernel_launch(void* const* d_in, const int* in_sizes, int n_in,
                              void* d_out, int out_size, void* d_ws, size_t ws_size,
                              hipStream_t stream) {
  const float* x = (const float*)d_in[0];
  const float* Wq = (const float*)d_in[1];
  const float* Wk = (const float*)d_in[2];
  const float* Wv = (const float*)d_in[3];
  const float* Wo = (const float*)d_in[4];

  char* w = (char*)d_ws;
  float* ropetab = (float*)w;  w += (size_t)SEQ * HD * 4;
  short* xb  = (short*)w;  w += (size_t)MTOT * DIM * 2;
  short* WqT = (short*)w;  w += (size_t)DIM * DIM * 2;
  short* WkT = (short*)w;  w += (size_t)(KVH * HD) * DIM * 2;
  short* WvT = (short*)w;  w += (size_t)(KVH * HD) * DIM * 2;
  short* WoT = (short*)w;  w += (size_t)DIM * DIM * 2;
  short* q_r = (short*)w;  w += (size_t)BATCH * NH * SEQ * HD * 2;
  short* k_r = (short*)w;  w += (size_t)BATCH * KVH * SEQ * HD * 2;
  short* v_r = (short*)w;  w += (size_t)BATCH * KVH * SEQ * HD * 2;
  short* attn = (short*)w; w += (size_t)MTOT * DIM * 2;
  // v_t aliases xb: xb's last reader is k_gemm_kv, which precedes k_transpose_v in-stream.
  short* v_t = xb;

  k_rope_table<<<SEQ, 64, 0, stream>>>(ropetab);
  k_cvt_bf16<<<(MTOT * DIM / 4 + 255) / 256, 256, 0, stream>>>(x, xb, MTOT * DIM / 4);
  k_transpose<<<dim3(DIM / 32, DIM / 32), 256, 0, stream>>>(Wq, WqT, DIM, DIM);
  k_transpose<<<dim3((KVH * HD) / 32, DIM / 32), 256, 0, stream>>>(Wk, WkT, DIM, KVH * HD);
  k_transpose<<<dim3((KVH * HD) / 32, DIM / 32), 256, 0, stream>>>(Wv, WvT, DIM, KVH * HD);
  k_transpose<<<dim3(DIM / 32, DIM / 32), 256, 0, stream>>>(Wo, WoT, DIM, DIM);

  k_gemm_q<<<dim3(DIM / 128, MTOT / 128), 256, 0, stream>>>(xb, WqT, q_r, MTOT, DIM, DIM);
  k_gemm_kv<<<dim3((KVH * HD) / 128, MTOT / 128, 2), 256, 0, stream>>>(xb, WkT, WvT, k_r, v_r,
                                                                       MTOT, KVH * HD, DIM);
  k_transpose_v<<<dim3(SEQ / 64, HD / 64, BATCH * KVH), 256, 0, stream>>>(v_r, v_t);
  k_rope<<<(BATCH * NH * SEQ * 64 + 255) / 256, 256, 0, stream>>>(q_r, ropetab, BATCH * NH * SEQ * 64, SCALE);
  k_rope<<<(BATCH * KVH * SEQ * 64 + 255) / 256, 256, 0, stream>>>(k_r, ropetab, BATCH * KVH * SEQ * 64, 1.0f);

  k_attn<<<dim3(SEQ / 64, BATCH * NH), 256, 0, stream>>>(q_r, k_r, v_t, attn);
  k_gemm_o<<<dim3(DIM / 128, MTOT / 128), 256, 0, stream>>>(attn, WoT, (float*)d_out, MTOT, DIM, DIM);
}

// Round 7
// 470.698 us; speedup vs baseline: 1.9259x; 1.9259x over previous
//
#include <hip/hip_runtime.h>
#include <hip/hip_bf16.h>

#define DIM 2048
#define NH 16
#define KVH 4
#define HD 128
#define BATCH 2
#define SEQ 2048
#define MTOT (BATCH*SEQ)
#define SCALE 0.08838834764831845f

using f32x4 = __attribute__((ext_vector_type(4))) float;
using s16x4 = __attribute__((ext_vector_type(4))) short;
using s16x8 = __attribute__((ext_vector_type(8))) short;
using bf16x8 = __attribute__((ext_vector_type(8))) __bf16;

__device__ inline short f2bf(float x) { __bf16 h = (__bf16)x; return __builtin_bit_cast(short, h); }
__device__ inline float bf2f(short s) { return (float)__builtin_bit_cast(__bf16, s); }

// Contiguous 8-elem fragment (single ds_read_b128 / global_load_dwordx4).
// Enumeration: lane l slot j <-> k = (l>>4)*8 + j. Valid whenever BOTH mfma
// operands use it (intra-K enumeration cancels; only C/D layout is HW-fixed).
__device__ inline bf16x8 ld_frag128(const short* p) {
  return __builtin_bit_cast(bf16x8, *(const s16x8*)p);
}

// Split 4+4 fragment at p / p+16 (two ds_read_b64). Enumeration:
// slot j<4 -> k=(l>>4)*4+j ; slot j>=4 -> k=16+(l>>4)*4+(j-4).
// Used for PV so the exp'd S registers ARE the P fragment.
__device__ inline bf16x8 ld_frag(const short* p) {
  s16x4 lo = *(const s16x4*)p;
  s16x4 hi = *(const s16x4*)(p + 16);
  s16x8 f = __builtin_shufflevector(lo, hi, 0, 1, 2, 3, 4, 5, 6, 7);
  return __builtin_bit_cast(bf16x8, f);
}

// Pack two f32x4 into a bf16x8 fragment (slots 0-3 = a, 4-7 = b).
__device__ inline bf16x8 pack_p(f32x4 a, f32x4 b) {
  bf16x8 o;
  o[0] = (__bf16)a[0]; o[1] = (__bf16)a[1]; o[2] = (__bf16)a[2]; o[3] = (__bf16)a[3];
  o[4] = (__bf16)b[0]; o[5] = (__bf16)b[1]; o[6] = (__bf16)b[2]; o[7] = (__bf16)b[3];
  return o;
}

// ---------------- prep kernels ----------------

__global__ void k_rope_table(float* __restrict__ tab) {
  int n = blockIdx.x, i = threadIdx.x;  // i in [0,64)
  float inv = expf(-(2.f * i / (float)HD) * logf(10000.f));
  float a = (float)n * inv;
  tab[n * HD + i] = cosf(a);
  tab[n * HD + 64 + i] = sinf(a);
}

__global__ void k_cvt_bf16(const float* __restrict__ in, short* __restrict__ out, int n4) {
  int i = blockIdx.x * 256 + threadIdx.x;
  if (i >= n4) return;
  f32x4 v = *(const f32x4*)(in + (size_t)i * 4);
  s16x4 o;
  o[0] = f2bf(v[0]); o[1] = f2bf(v[1]); o[2] = f2bf(v[2]); o[3] = f2bf(v[3]);
  *(s16x4*)(out + (size_t)i * 4) = o;
}

// W f32 [K][N] -> WT bf16 [N][K]
__global__ __launch_bounds__(256) void k_transpose(const float* __restrict__ W, short* __restrict__ WT,
                                                   int K, int N) {
  __shared__ float t[32][33];
  int n0 = blockIdx.x * 32, k0 = blockIdx.y * 32;
  int tx = threadIdx.x & 31, ty = threadIdx.x >> 5;
#pragma unroll
  for (int i = 0; i < 4; i++) t[ty + i * 8][tx] = W[(size_t)(k0 + ty + i * 8) * N + n0 + tx];
  __syncthreads();
#pragma unroll
  for (int i = 0; i < 4; i++) WT[(size_t)(n0 + ty + i * 8) * K + k0 + tx] = f2bf(t[tx][ty + i * 8]);
}

// V bf16 [.][SEQ][HD] -> [.][HD][SEQ], 64x64 tiles
__global__ __launch_bounds__(256) void k_transpose_v(const short* __restrict__ v_r, short* __restrict__ v_t) {
  __shared__ short t[64][70];
  const int z = blockIdx.z;
  const int s0 = blockIdx.x * 64, d0 = blockIdx.y * 64;
  const long ibase = ((long)z * SEQ + s0) * HD + d0;
  const long obase = ((long)z * HD + d0) * SEQ + s0;
  const int tid = threadIdx.x;
#pragma unroll
  for (int c = 0; c < 4; c++) {
    int chunk = tid + c * 256;              // 0..1023
    int row = chunk >> 4, col4 = (chunk & 15) * 4;
    *(s16x4*)&t[row][col4] = *(const s16x4*)(v_r + ibase + (long)row * HD + col4);
  }
  __syncthreads();
#pragma unroll
  for (int c = 0; c < 4; c++) {
    int chunk = tid + c * 256;
    int row = chunk >> 4, col4 = (chunk & 15) * 4; // row: hd idx, col4: seq chunk
    s16x4 o;
    o[0] = t[col4 + 0][row]; o[1] = t[col4 + 1][row];
    o[2] = t[col4 + 2][row]; o[3] = t[col4 + 3][row];
    *(s16x4*)(v_t + obase + (long)row * SEQ + col4) = o;
  }
}

// ---------------- GEMM: C = A @ BT^T (m97 structure: 128x128 tile, BK=32, b128 frags) ----------------
// A [M][K] bf16 rm, BT [N][K] bf16 rm.
// MODE 0: C fp32 [M][N].  MODE 1: C bf16 permuted to [B][HH][SEQ][HD].
template <int MODE, int HH>
__device__ inline void gemm_bt_body(const short* __restrict__ A, const short* __restrict__ BT,
                                    void* __restrict__ C, int M, int N, int K) {
  __shared__ short As[128 * 32];
  __shared__ short Bs[128 * 32];
  const int tid = threadIdx.x;
  const int wid = tid >> 6, lane = tid & 63;
  const int m0 = blockIdx.y * 128, n0 = blockIdx.x * 128;
  const int wr = wid >> 1, wc = wid & 1;
  const int l15 = lane & 15, g4 = (lane >> 4) * 4, kg8 = (lane >> 4) * 8;
  const int lrow = lane >> 2;         // 0..15
  const int lcol = (lane & 3) * 8;    // 0,8,16,24
  f32x4 acc[4][4] = {};

  for (int kt = 0; kt < K; kt += 32) {
    __syncthreads();
#pragma unroll
    for (int i = 0; i < 2; i++) {
      int r0 = wid * 32 + i * 16;
      const short* gp = A + (long)(m0 + r0 + lrow) * K + kt + lcol;
      __builtin_amdgcn_global_load_lds((const __attribute__((address_space(1))) void*)gp,
                                       (__attribute__((address_space(3))) void*)&As[r0 * 32], 16, 0, 0);
      const short* gq = BT + (long)(n0 + r0 + lrow) * K + kt + lcol;
      __builtin_amdgcn_global_load_lds((const __attribute__((address_space(1))) void*)gq,
                                       (__attribute__((address_space(3))) void*)&Bs[r0 * 32], 16, 0, 0);
    }
    __syncthreads();
    bf16x8 av[4];
#pragma unroll
    for (int mt = 0; mt < 4; mt++) av[mt] = ld_frag128(&As[(wr * 64 + mt * 16 + l15) * 32 + kg8]);
#pragma unroll
    for (int nt = 0; nt < 4; nt++) {
      bf16x8 bv = ld_frag128(&Bs[(wc * 64 + nt * 16 + l15) * 32 + kg8]);
#pragma unroll
      for (int mt = 0; mt < 4; mt++)
        acc[mt][nt] = __builtin_amdgcn_mfma_f32_16x16x32_bf16(av[mt], bv, acc[mt][nt], 0, 0, 0);
    }
  }

#pragma unroll
  for (int mt = 0; mt < 4; mt++) {
#pragma unroll
    for (int nt = 0; nt < 4; nt++) {
      int row = m0 + wr * 64 + mt * 16 + g4;
      int col = n0 + wc * 64 + nt * 16 + l15;
#pragma unroll
      for (int r = 0; r < 4; r++) {
        float v = acc[mt][nt][r];
        if (MODE == 0) {
          ((float*)C)[(long)(row + r) * N + col] = v;
        } else {
          int rg = row + r;
          int b = rg >> 11, n = rg & (SEQ - 1);
          int h = col >> 7, hd = col & (HD - 1);
          ((short*)C)[(((long)(b * HH + h)) * SEQ + n) * HD + hd] = f2bf(v);
        }
      }
    }
  }
}

__global__ __launch_bounds__(256) void k_gemm_q(const short* __restrict__ A, const short* __restrict__ BT,
                                                short* __restrict__ C, int M, int N, int K) {
  gemm_bt_body<1, NH>(A, BT, (void*)C, M, N, K);
}
__global__ __launch_bounds__(256) void k_gemm_kv(const short* __restrict__ A,
                                                 const short* __restrict__ BT0, const short* __restrict__ BT1,
                                                 short* __restrict__ C0, short* __restrict__ C1,
                                                 int M, int N, int K) {
  const short* BT = blockIdx.z ? BT1 : BT0;
  short* C = blockIdx.z ? C1 : C0;
  gemm_bt_body<1, KVH>(A, BT, (void*)C, M, N, K);
}
__global__ __launch_bounds__(256) void k_gemm_o(const short* __restrict__ A, const short* __restrict__ BT,
                                                float* __restrict__ C, int M, int N, int K) {
  gemm_bt_body<0, 0>(A, BT, (void*)C, M, N, K);
}

// ---------------- RoPE in-place on [.][heads][SEQ][HD] bf16, optional scale fold ----------------
__global__ void k_rope(short* __restrict__ t, const float* __restrict__ tab, int total, float scale) {
  int idx = blockIdx.x * 256 + threadIdx.x;
  if (idx >= total) return;
  int i = idx & 63;
  int n = (idx >> 6) & (SEQ - 1);
  long base = (long)(idx >> 6) * HD;
  float c = tab[n * HD + i], s = tab[n * HD + 64 + i];
  float x1 = bf2f(t[base + i]), x2 = bf2f(t[base + 64 + i]);
  t[base + i] = f2bf((x1 * c - x2 * s) * scale);
  t[base + 64 + i] = f2bf((x2 * c + x1 * s) * scale);
}

// ---------------- flash attention (swapped QK^T: S = [kv regs][q lanes]) ----------------
// q_r [B][NH][SEQ][HD] (pre-scaled), k_r [B][KVH][SEQ][HD], v_t [B][KVH][HD][SEQ] bf16
// out [B*SEQ][NH*HD] bf16
__global__ __launch_bounds__(256, 4) void k_attn(const short* __restrict__ q_r, const short* __restrict__ k_r,
                                                 const short* __restrict__ v_t, short* __restrict__ attn_out) {
  __shared__ short Kl[64 * 136];      // [kv 64][hd 128 pad 136]
  __shared__ short Vt[128 * 68];      // [hd 128][kv 64 pad 68]
  const int tid = threadIdx.x, wid = tid >> 6, lane = tid & 63;
  const int l15 = lane & 15, g4 = (lane >> 4) * 4, kg8 = (lane >> 4) * 8;
  const int qt = (int)(gridDim.x - 1) - blockIdx.x;  // heavy blocks first
  const int bh = blockIdx.y;
  const int b = bh >> 4, h = bh & 15, kvh = h >> 2;
  const int q0 = qt * 64;

  // Q fragment (contiguous enum): lane l15 holds q-row (q0 + wid*16 + l15)
  const long qbase = (((long)(b * NH + h)) * SEQ + q0 + wid * 16) * HD;
  bf16x8 aq[4];
#pragma unroll
  for (int kt = 0; kt < 4; kt++) aq[kt] = ld_frag128(q_r + qbase + (long)l15 * HD + kt * 32 + kg8);

  f32x4 acc[8] = {};
  float m_ = -1e30f, l_ = 0.f;        // per lane: stats for q = q0+wid*16+l15
  const long kvbase = ((long)(b * KVH + kvh)) * SEQ * HD;   // k_r head base
  const long vtbase = ((long)(b * KVH + kvh)) * HD * SEQ;   // v_t head base
  const int nkt = qt + 1;
  const int qg = q0 + wid * 16 + l15;

  // T14 async-stage: tile t+1 global->reg issued under tile t compute
  s16x8 kreg[4], vreg[4];
#pragma unroll
  for (int c = 0; c < 4; c++) {
    int chunk = tid + c * 256;
    int kr = chunk >> 4, kc = (chunk & 15) * 8;
    kreg[c] = *(const s16x8*)(k_r + kvbase + (long)kr * HD + kc);
    int vr = chunk >> 3, vc = (chunk & 7) * 8;
    vreg[c] = *(const s16x8*)(v_t + vtbase + (long)vr * SEQ + vc);
  }

  for (int t64 = 0; t64 < nkt; t64++) {
    __syncthreads();  // previous-iteration LDS reads done
#pragma unroll
    for (int c = 0; c < 4; c++) {
      int chunk = tid + c * 256;
      int kr = chunk >> 4, kc = (chunk & 15) * 8;
      *(s16x8*)&Kl[kr * 136 + kc] = kreg[c];
      int vr = chunk >> 3, vc = (chunk & 7) * 8;
      *(s16x8*)&Vt[vr * 68 + vc] = vreg[c];
    }
    __syncthreads();

    if (t64 + 1 < nkt) {
      const int kv0n = (t64 + 1) * 64;
#pragma unroll
      for (int c = 0; c < 4; c++) {
        int chunk = tid + c * 256;
        int kr = chunk >> 4, kc = (chunk & 15) * 8;
        kreg[c] = *(const s16x8*)(k_r + kvbase + (long)(kv0n + kr) * HD + kc);
        int vr = chunk >> 3, vc = (chunk & 7) * 8;
        vreg[c] = *(const s16x8*)(v_t + vtbase + (long)vr * SEQ + kv0n + vc);
      }
    }

    const int kv0 = t64 * 64;
    // S = K @ Q^T: s[nt][r] = S[kv = kv0+nt*16+g4+r][q = qg]  (A=K so kv lands in regs)
    f32x4 s[4] = {};
#pragma unroll
    for (int nt = 0; nt < 4; nt++) {
#pragma unroll
      for (int kt = 0; kt < 4; kt++) {
        bf16x8 bk = ld_frag128(&Kl[(nt * 16 + l15) * 136 + kt * 32 + kg8]);
        s[nt] = __builtin_amdgcn_mfma_f32_16x16x32_bf16(bk, aq[kt], s[nt], 0, 0, 0);
      }
    }

    // causal mask: kv > q -> -inf
#pragma unroll
    for (int nt = 0; nt < 4; nt++) {
      int kvb = kv0 + nt * 16 + g4;
#pragma unroll
      for (int r = 0; r < 4; r++)
        s[nt][r] = (kvb + r > qg) ? -1e30f : s[nt][r];
    }

    // online softmax, in-register over 16 kv values + 2 cross-hi shfls
    float tm = -1e30f;
#pragma unroll
    for (int nt = 0; nt < 4; nt++) {
      float a = fmaxf(s[nt][0], s[nt][1]), bmx = fmaxf(s[nt][2], s[nt][3]);
      tm = fmaxf(tm, fmaxf(a, bmx));
    }
    tm = fmaxf(tm, __shfl_xor(tm, 16));
    tm = fmaxf(tm, __shfl_xor(tm, 32));
    float mn = fmaxf(m_, tm);
    float corr = __expf(m_ - mn);
    m_ = mn;
    float rs = 0.f;
#pragma unroll
    for (int nt = 0; nt < 4; nt++)
#pragma unroll
      for (int r = 0; r < 4; r++) {
        float p = __expf(s[nt][r] - mn);
        s[nt][r] = p;
        rs += p;
      }
    rs += __shfl_xor(rs, 16);
    rs += __shfl_xor(rs, 32);
    l_ = l_ * corr + rs;

    // corr to reg-space (acc reg r holds q = q0+wid*16+g4+r; that q's stats sit in lane g4+r)
    float corr_r[4];
#pragma unroll
    for (int r = 0; r < 4; r++) corr_r[r] = __shfl(corr, g4 + r);
#pragma unroll
    for (int dt = 0; dt < 8; dt++)
#pragma unroll
      for (int r = 0; r < 4; r++) acc[dt][r] *= corr_r[r];

    // P fragments ARE the exp'd S regs (split enum: slot j = kv hi*4+j / 16+hi*4+j)
    bf16x8 pa0 = pack_p(s[0], s[1]);
    bf16x8 pa1 = pack_p(s[2], s[3]);

    // O += P @ V  (V uses the matching split enum via ld_frag)
#pragma unroll
    for (int dt = 0; dt < 8; dt++) {
      bf16x8 bv0 = ld_frag(&Vt[(dt * 16 + l15) * 68 + g4]);
      acc[dt] = __builtin_amdgcn_mfma_f32_16x16x32_bf16(pa0, bv0, acc[dt], 0, 0, 0);
      bf16x8 bv1 = ld_frag(&Vt[(dt * 16 + l15) * 68 + 32 + g4]);
      acc[dt] = __builtin_amdgcn_mfma_f32_16x16x32_bf16(pa1, bv1, acc[dt], 0, 0, 0);
    }
  }

  float inv = 1.f / l_;
  float inv_r[4];
#pragma unroll
  for (int r = 0; r < 4; r++) inv_r[r] = __shfl(inv, g4 + r);

  const long obase = ((long)(b * SEQ + q0 + wid * 16 + g4)) * (NH * HD) + (long)h * HD;
#pragma unroll
  for (int r = 0; r < 4; r++) {
#pragma unroll
    for (int dt = 0; dt < 8; dt++)
      attn_out[obase + (long)r * (NH * HD) + dt * 16 + l15] = f2bf(acc[dt][r] * inv_r[r]);
  }
}

// ---------------- launch ----------------
extern "C" void kernel_launch(void* const* d_in, const int* in_sizes, int n_in,
                              void* d_out, int out_size, void* d_ws, size_t ws_size,
                              hipStream_t stream) {
  const float* x = (const float*)d_in[0];
  const float* Wq = (const float*)d_in[1];
  const float* Wk = (const float*)d_in[2];
  const float* Wv = (const float*)d_in[3];
  const float* Wo = (const float*)d_in[4];

  char* w = (char*)d_ws;
  float* ropetab = (float*)w;  w += (size_t)SEQ * HD * 4;
  short* xb  = (short*)w;  w += (size_t)MTOT * DIM * 2;
  short* WqT = (short*)w;  w += (size_t)DIM * DIM * 2;
  short* WkT = (short*)w;  w += (size_t)(KVH * HD) * DIM * 2;
  short* WvT = (short*)w;  w += (size_t)(KVH * HD) * DIM * 2;
  short* WoT = (short*)w;  w += (size_t)DIM * DIM * 2;
  short* q_r = (short*)w;  w += (size_t)BATCH * NH * SEQ * HD * 2;
  short* k_r = (short*)w;  w += (size_t)BATCH * KVH * SEQ * HD * 2;
  short* v_r = (short*)w;  w += (size_t)BATCH * KVH * SEQ * HD * 2;
  short* attn = (short*)w; w += (size_t)MTOT * DIM * 2;
  // v_t aliases xb: xb's last reader is k_gemm_kv, which precedes k_transpose_v in-stream.
  short* v_t = xb;

  k_rope_table<<<SEQ, 64, 0, stream>>>(ropetab);
  k_cvt_bf16<<<(MTOT * DIM / 4 + 255) / 256, 256, 0, stream>>>(x, xb, MTOT * DIM / 4);
  k_transpose<<<dim3(DIM / 32, DIM / 32), 256, 0, stream>>>(Wq, WqT, DIM, DIM);
  k_transpose<<<dim3((KVH * HD) / 32, DIM / 32), 256, 0, stream>>>(Wk, WkT, DIM, KVH * HD);
  k_transpose<<<dim3((KVH * HD) / 32, DIM / 32), 256, 0, stream>>>(Wv, WvT, DIM, KVH * HD);
  k_transpose<<<dim3(DIM / 32, DIM / 32), 256, 0, stream>>>(Wo, WoT, DIM, DIM);

  k_gemm_q<<<dim3(DIM / 128, MTOT / 128), 256, 0, stream>>>(xb, WqT, q_r, MTOT, DIM, DIM);
  k_gemm_kv<<<dim3((KVH * HD) / 128, MTOT / 128, 2), 256, 0, stream>>>(xb, WkT, WvT, k_r, v_r,
                                                                       MTOT, KVH * HD, DIM);
  k_transpose_v<<<dim3(SEQ / 64, HD / 64, BATCH * KVH), 256, 0, stream>>>(v_r, v_t);
  k_rope<<<(BATCH * NH * SEQ * 64 + 255) / 256, 256, 0, stream>>>(q_r, ropetab, BATCH * NH * SEQ * 64, SCALE);
  k_rope<<<(BATCH * KVH * SEQ * 64 + 255) / 256, 256, 0, stream>>>(k_r, ropetab, BATCH * KVH * SEQ * 64, 1.0f);

  k_attn<<<dim3(SEQ / 64, BATCH * NH), 256, 0, stream>>>(q_r, k_r, v_t, attn);
  k_gemm_o<<<dim3(DIM / 128, MTOT / 128), 256, 0, stream>>>(attn, WoT, (float*)d_out, MTOT, DIM, DIM);
}

// Round 8
// 361.308 us; speedup vs baseline: 2.5090x; 1.3028x over previous
//
#include <hip/hip_runtime.h>
#include <hip/hip_bf16.h>

#define DIM 2048
#define NH 16
#define KVH 4
#define HD 128
#define BATCH 2
#define SEQ 2048
#define MTOT (BATCH*SEQ)
#define SCALE 0.08838834764831845f
// SCALE * log2(e): QK^T scores land in log2 units -> exp2f softmax
#define SCALE_L2E 0.12751743762f

using f32x4 = __attribute__((ext_vector_type(4))) float;
using s16x4 = __attribute__((ext_vector_type(4))) short;
using s16x8 = __attribute__((ext_vector_type(8))) short;
using bf16x8 = __attribute__((ext_vector_type(8))) __bf16;

__device__ inline short f2bf(float x) { __bf16 h = (__bf16)x; return __builtin_bit_cast(short, h); }
__device__ inline float bf2f(short s) { return (float)__builtin_bit_cast(__bf16, s); }

// Contiguous 8-elem fragment (single ds_read_b128). Enumeration k=(l>>4)*8+j;
// valid when BOTH mfma operands use it (intra-K enumeration cancels).
__device__ inline bf16x8 ld_frag128(const short* p) {
  return __builtin_bit_cast(bf16x8, *(const s16x8*)p);
}

// Split 4+4 fragment at p / p+16 (two ds_read_b64). slot j<4 -> k=(l>>4)*4+j,
// j>=4 -> k=16+(l>>4)*4+(j-4). Matches pack_p(s) so exp'd S regs ARE P.
__device__ inline bf16x8 ld_frag(const short* p) {
  s16x4 lo = *(const s16x4*)p;
  s16x4 hi = *(const s16x4*)(p + 16);
  s16x8 f = __builtin_shufflevector(lo, hi, 0, 1, 2, 3, 4, 5, 6, 7);
  return __builtin_bit_cast(bf16x8, f);
}

__device__ inline bf16x8 pack_p(f32x4 a, f32x4 b) {
  bf16x8 o;
  o[0] = (__bf16)a[0]; o[1] = (__bf16)a[1]; o[2] = (__bf16)a[2]; o[3] = (__bf16)a[3];
  o[4] = (__bf16)b[0]; o[5] = (__bf16)b[1]; o[6] = (__bf16)b[2]; o[7] = (__bf16)b[3];
  return o;
}

// ---------------- prep kernels ----------------

__global__ void k_rope_table(float* __restrict__ tab) {
  int n = blockIdx.x, i = threadIdx.x;  // i in [0,64)
  float inv = expf(-(2.f * i / (float)HD) * logf(10000.f));
  float a = (float)n * inv;
  tab[n * HD + i] = cosf(a);
  tab[n * HD + 64 + i] = sinf(a);
}

__global__ void k_cvt_bf16(const float* __restrict__ in, short* __restrict__ out, int n4) {
  int i = blockIdx.x * 256 + threadIdx.x;
  if (i >= n4) return;
  f32x4 v = *(const f32x4*)(in + (size_t)i * 4);
  s16x4 o;
  o[0] = f2bf(v[0]); o[1] = f2bf(v[1]); o[2] = f2bf(v[2]); o[3] = f2bf(v[3]);
  *(s16x4*)(out + (size_t)i * 4) = o;
}

// W f32 [K][N] -> WT bf16 [N][K]
__global__ __launch_bounds__(256) void k_transpose(const float* __restrict__ W, short* __restrict__ WT,
                                                   int K, int N) {
  __shared__ float t[32][33];
  int n0 = blockIdx.x * 32, k0 = blockIdx.y * 32;
  int tx = threadIdx.x & 31, ty = threadIdx.x >> 5;
#pragma unroll
  for (int i = 0; i < 4; i++) t[ty + i * 8][tx] = W[(size_t)(k0 + ty + i * 8) * N + n0 + tx];
  __syncthreads();
#pragma unroll
  for (int i = 0; i < 4; i++) WT[(size_t)(n0 + ty + i * 8) * K + k0 + tx] = f2bf(t[tx][ty + i * 8]);
}

// V bf16 [.][SEQ][HD] -> [.][HD][SEQ], 64x64 tiles
__global__ __launch_bounds__(256) void k_transpose_v(const short* __restrict__ v_r, short* __restrict__ v_t) {
  __shared__ short t[64][70];
  const int z = blockIdx.z;
  const int s0 = blockIdx.x * 64, d0 = blockIdx.y * 64;
  const long ibase = ((long)z * SEQ + s0) * HD + d0;
  const long obase = ((long)z * HD + d0) * SEQ + s0;
  const int tid = threadIdx.x;
#pragma unroll
  for (int c = 0; c < 4; c++) {
    int chunk = tid + c * 256;              // 0..1023
    int row = chunk >> 4, col4 = (chunk & 15) * 4;
    *(s16x4*)&t[row][col4] = *(const s16x4*)(v_r + ibase + (long)row * HD + col4);
  }
  __syncthreads();
#pragma unroll
  for (int c = 0; c < 4; c++) {
    int chunk = tid + c * 256;
    int row = chunk >> 4, col4 = (chunk & 15) * 4; // row: hd idx, col4: seq chunk
    s16x4 o;
    o[0] = t[col4 + 0][row]; o[1] = t[col4 + 1][row];
    o[2] = t[col4 + 2][row]; o[3] = t[col4 + 3][row];
    *(s16x4*)(v_t + obase + (long)row * SEQ + col4) = o;
  }
}

// ---------------- GEMM: C = A @ BT^T (128x128 tile, BK=32, b128 frags) ----------------
template <int MODE, int HH>
__device__ inline void gemm_bt_body(const short* __restrict__ A, const short* __restrict__ BT,
                                    void* __restrict__ C, int M, int N, int K) {
  __shared__ short As[128 * 32];
  __shared__ short Bs[128 * 32];
  const int tid = threadIdx.x;
  const int wid = tid >> 6, lane = tid & 63;
  const int m0 = blockIdx.y * 128, n0 = blockIdx.x * 128;
  const int wr = wid >> 1, wc = wid & 1;
  const int l15 = lane & 15, g4 = (lane >> 4) * 4, kg8 = (lane >> 4) * 8;
  const int lrow = lane >> 2;         // 0..15
  const int lcol = (lane & 3) * 8;    // 0,8,16,24
  f32x4 acc[4][4] = {};

  for (int kt = 0; kt < K; kt += 32) {
    __syncthreads();
#pragma unroll
    for (int i = 0; i < 2; i++) {
      int r0 = wid * 32 + i * 16;
      const short* gp = A + (long)(m0 + r0 + lrow) * K + kt + lcol;
      __builtin_amdgcn_global_load_lds((const __attribute__((address_space(1))) void*)gp,
                                       (__attribute__((address_space(3))) void*)&As[r0 * 32], 16, 0, 0);
      const short* gq = BT + (long)(n0 + r0 + lrow) * K + kt + lcol;
      __builtin_amdgcn_global_load_lds((const __attribute__((address_space(1))) void*)gq,
                                       (__attribute__((address_space(3))) void*)&Bs[r0 * 32], 16, 0, 0);
    }
    __syncthreads();
    bf16x8 av[4];
#pragma unroll
    for (int mt = 0; mt < 4; mt++) av[mt] = ld_frag128(&As[(wr * 64 + mt * 16 + l15) * 32 + kg8]);
#pragma unroll
    for (int nt = 0; nt < 4; nt++) {
      bf16x8 bv = ld_frag128(&Bs[(wc * 64 + nt * 16 + l15) * 32 + kg8]);
#pragma unroll
      for (int mt = 0; mt < 4; mt++)
        acc[mt][nt] = __builtin_amdgcn_mfma_f32_16x16x32_bf16(av[mt], bv, acc[mt][nt], 0, 0, 0);
    }
  }

#pragma unroll
  for (int mt = 0; mt < 4; mt++) {
#pragma unroll
    for (int nt = 0; nt < 4; nt++) {
      int row = m0 + wr * 64 + mt * 16 + g4;
      int col = n0 + wc * 64 + nt * 16 + l15;
#pragma unroll
      for (int r = 0; r < 4; r++) {
        float v = acc[mt][nt][r];
        if (MODE == 0) {
          ((float*)C)[(long)(row + r) * N + col] = v;
        } else {
          int rg = row + r;
          int b = rg >> 11, n = rg & (SEQ - 1);
          int h = col >> 7, hd = col & (HD - 1);
          ((short*)C)[(((long)(b * HH + h)) * SEQ + n) * HD + hd] = f2bf(v);
        }
      }
    }
  }
}

__global__ __launch_bounds__(256) void k_gemm_q(const short* __restrict__ A, const short* __restrict__ BT,
                                                short* __restrict__ C, int M, int N, int K) {
  gemm_bt_body<1, NH>(A, BT, (void*)C, M, N, K);
}
__global__ __launch_bounds__(256) void k_gemm_kv(const short* __restrict__ A,
                                                 const short* __restrict__ BT0, const short* __restrict__ BT1,
                                                 short* __restrict__ C0, short* __restrict__ C1,
                                                 int M, int N, int K) {
  const short* BT = blockIdx.z ? BT1 : BT0;
  short* C = blockIdx.z ? C1 : C0;
  gemm_bt_body<1, KVH>(A, BT, (void*)C, M, N, K);
}
__global__ __launch_bounds__(256) void k_gemm_o(const short* __restrict__ A, const short* __restrict__ BT,
                                                float* __restrict__ C, int M, int N, int K) {
  gemm_bt_body<0, 0>(A, BT, (void*)C, M, N, K);
}

// ---------------- RoPE in-place on [.][heads][SEQ][HD] bf16, optional scale fold ----------------
__global__ void k_rope(short* __restrict__ t, const float* __restrict__ tab, int total, float scale) {
  int idx = blockIdx.x * 256 + threadIdx.x;
  if (idx >= total) return;
  int i = idx & 63;
  int n = (idx >> 6) & (SEQ - 1);
  long base = (long)(idx >> 6) * HD;
  float c = tab[n * HD + i], s = tab[n * HD + 64 + i];
  float x1 = bf2f(t[base + i]), x2 = bf2f(t[base + 64 + i]);
  t[base + i] = f2bf((x1 * c - x2 * s) * scale);
  t[base + 64 + i] = f2bf((x2 * c + x1 * s) * scale);
}

// ---------------- flash attention (paired q-tiles, swapped QK^T) ----------------
// Block handles q-tiles qlo=blockIdx.x and qhi=31-blockIdx.x in ONE fused KV loop:
// constant 33 tiles of q-work per block (perfect balance), KV prefix staged once.
// q_r pre-scaled by SCALE*log2(e) -> softmax in exp2 domain.
__global__ __launch_bounds__(256, 2) void k_attn(const short* __restrict__ q_r, const short* __restrict__ k_r,
                                                 const short* __restrict__ v_t, short* __restrict__ attn_out) {
  __shared__ short Kl[64 * 136];      // [kv 64][hd 128 pad 136]
  __shared__ short Vt[128 * 68];      // [hd 128][kv 64 pad 68]
  const int tid = threadIdx.x, wid = tid >> 6, lane = tid & 63;
  const int l15 = lane & 15, g4 = (lane >> 4) * 4, kg8 = (lane >> 4) * 8;
  const int qlo = blockIdx.x;               // 0..15
  const int qhi = 31 - qlo;                 // 16..31
  const int bh = blockIdx.y;
  const int b = bh >> 4, h = bh & 15, kvh = h >> 2;

  const long hbase = ((long)(b * NH + h)) * SEQ;
  bf16x8 aqL[4], aqH[4];
#pragma unroll
  for (int kt = 0; kt < 4; kt++) {
    aqL[kt] = ld_frag128(q_r + (hbase + qlo * 64 + wid * 16 + l15) * HD + kt * 32 + kg8);
    aqH[kt] = ld_frag128(q_r + (hbase + qhi * 64 + wid * 16 + l15) * HD + kt * 32 + kg8);
  }

  f32x4 accL[8] = {}, accH[8] = {};
  float mL = -1e30f, lL = 0.f, mH = -1e30f, lH = 0.f;
  const long kvbase = ((long)(b * KVH + kvh)) * SEQ * HD;
  const long vtbase = ((long)(b * KVH + kvh)) * HD * SEQ;
  const int qgL = qlo * 64 + wid * 16 + l15;
  const int qgH = qhi * 64 + wid * 16 + l15;

  s16x8 kreg[4], vreg[4];
#pragma unroll
  for (int c = 0; c < 4; c++) {
    int chunk = tid + c * 256;
    int kr = chunk >> 4, kc = (chunk & 15) * 8;
    kreg[c] = *(const s16x8*)(k_r + kvbase + (long)kr * HD + kc);
    int vr = chunk >> 3, vc = (chunk & 7) * 8;
    vreg[c] = *(const s16x8*)(v_t + vtbase + (long)vr * SEQ + vc);
  }

  for (int t64 = 0; t64 <= qhi; t64++) {
    __syncthreads();
#pragma unroll
    for (int c = 0; c < 4; c++) {
      int chunk = tid + c * 256;
      int kr = chunk >> 4, kc = (chunk & 15) * 8;
      *(s16x8*)&Kl[kr * 136 + kc] = kreg[c];
      int vr = chunk >> 3, vc = (chunk & 7) * 8;
      *(s16x8*)&Vt[vr * 68 + vc] = vreg[c];
    }
    __syncthreads();

    if (t64 < qhi) {
      const int kv0n = (t64 + 1) * 64;
#pragma unroll
      for (int c = 0; c < 4; c++) {
        int chunk = tid + c * 256;
        int kr = chunk >> 4, kc = (chunk & 15) * 8;
        kreg[c] = *(const s16x8*)(k_r + kvbase + (long)(kv0n + kr) * HD + kc);
        int vr = chunk >> 3, vc = (chunk & 7) * 8;
        vreg[c] = *(const s16x8*)(v_t + vtbase + (long)vr * SEQ + kv0n + vc);
      }
    }

    const int kv0 = t64 * 64;
    const bool actL = (t64 <= qlo);

    // QK^T (swapped: kv in regs, q in lanes) for both tiles
    f32x4 sH[4] = {}, sL[4] = {};
#pragma unroll
    for (int nt = 0; nt < 4; nt++) {
#pragma unroll
      for (int kt = 0; kt < 4; kt++) {
        bf16x8 bk = ld_frag128(&Kl[(nt * 16 + l15) * 136 + kt * 32 + kg8]);
        sH[nt] = __builtin_amdgcn_mfma_f32_16x16x32_bf16(bk, aqH[kt], sH[nt], 0, 0, 0);
        if (actL) sL[nt] = __builtin_amdgcn_mfma_f32_16x16x32_bf16(bk, aqL[kt], sL[nt], 0, 0, 0);
      }
    }

    // causal mask (only the diagonal tile of each q-tile needs it)
    if (t64 == qhi) {
#pragma unroll
      for (int nt = 0; nt < 4; nt++) {
        int kvb = kv0 + nt * 16 + g4;
#pragma unroll
        for (int r = 0; r < 4; r++) sH[nt][r] = (kvb + r > qgH) ? -1e30f : sH[nt][r];
      }
    }
    if (actL && t64 == qlo) {
#pragma unroll
      for (int nt = 0; nt < 4; nt++) {
        int kvb = kv0 + nt * 16 + g4;
#pragma unroll
        for (int r = 0; r < 4; r++) sL[nt][r] = (kvb + r > qgL) ? -1e30f : sL[nt][r];
      }
    }

    // ---- softmax + PV for H ----
    {
      float tm = -1e30f;
#pragma unroll
      for (int nt = 0; nt < 4; nt++)
        tm = fmaxf(tm, fmaxf(fmaxf(sH[nt][0], sH[nt][1]), fmaxf(sH[nt][2], sH[nt][3])));
      tm = fmaxf(tm, __shfl_xor(tm, 16));
      tm = fmaxf(tm, __shfl_xor(tm, 32));
      if (!__all(tm - mH <= 8.f)) {          // T13 defer-rescale
        float mn = fmaxf(mH, tm);
        float corr = exp2f(mH - mn);
        mH = mn;
        lH *= corr;
        float corr_r[4];
#pragma unroll
        for (int r = 0; r < 4; r++) corr_r[r] = __shfl(corr, g4 + r);
#pragma unroll
        for (int dt = 0; dt < 8; dt++)
#pragma unroll
          for (int r = 0; r < 4; r++) accH[dt][r] *= corr_r[r];
      }
      float rs = 0.f;
#pragma unroll
      for (int nt = 0; nt < 4; nt++)
#pragma unroll
        for (int r = 0; r < 4; r++) {
          float p = exp2f(sH[nt][r] - mH);
          sH[nt][r] = p;
          rs += p;
        }
      rs += __shfl_xor(rs, 16);
      rs += __shfl_xor(rs, 32);
      lH += rs;
      bf16x8 pa0 = pack_p(sH[0], sH[1]);
      bf16x8 pa1 = pack_p(sH[2], sH[3]);
#pragma unroll
      for (int dt = 0; dt < 8; dt++) {
        bf16x8 bv0 = ld_frag(&Vt[(dt * 16 + l15) * 68 + g4]);
        accH[dt] = __builtin_amdgcn_mfma_f32_16x16x32_bf16(pa0, bv0, accH[dt], 0, 0, 0);
        bf16x8 bv1 = ld_frag(&Vt[(dt * 16 + l15) * 68 + 32 + g4]);
        accH[dt] = __builtin_amdgcn_mfma_f32_16x16x32_bf16(pa1, bv1, accH[dt], 0, 0, 0);
      }
    }

    // ---- softmax + PV for L ----
    if (actL) {
      float tm = -1e30f;
#pragma unroll
      for (int nt = 0; nt < 4; nt++)
        tm = fmaxf(tm, fmaxf(fmaxf(sL[nt][0], sL[nt][1]), fmaxf(sL[nt][2], sL[nt][3])));
      tm = fmaxf(tm, __shfl_xor(tm, 16));
      tm = fmaxf(tm, __shfl_xor(tm, 32));
      if (!__all(tm - mL <= 8.f)) {
        float mn = fmaxf(mL, tm);
        float corr = exp2f(mL - mn);
        mL = mn;
        lL *= corr;
        float corr_r[4];
#pragma unroll
        for (int r = 0; r < 4; r++) corr_r[r] = __shfl(corr, g4 + r);
#pragma unroll
        for (int dt = 0; dt < 8; dt++)
#pragma unroll
          for (int r = 0; r < 4; r++) accL[dt][r] *= corr_r[r];
      }
      float rs = 0.f;
#pragma unroll
      for (int nt = 0; nt < 4; nt++)
#pragma unroll
        for (int r = 0; r < 4; r++) {
          float p = exp2f(sL[nt][r] - mL);
          sL[nt][r] = p;
          rs += p;
        }
      rs += __shfl_xor(rs, 16);
      rs += __shfl_xor(rs, 32);
      lL += rs;
      bf16x8 pa0 = pack_p(sL[0], sL[1]);
      bf16x8 pa1 = pack_p(sL[2], sL[3]);
#pragma unroll
      for (int dt = 0; dt < 8; dt++) {
        bf16x8 bv0 = ld_frag(&Vt[(dt * 16 + l15) * 68 + g4]);
        accL[dt] = __builtin_amdgcn_mfma_f32_16x16x32_bf16(pa0, bv0, accL[dt], 0, 0, 0);
        bf16x8 bv1 = ld_frag(&Vt[(dt * 16 + l15) * 68 + 32 + g4]);
        accL[dt] = __builtin_amdgcn_mfma_f32_16x16x32_bf16(pa1, bv1, accL[dt], 0, 0, 0);
      }
    }
  }

  // epilogue: both tiles
  {
    float inv = 1.f / lH;
    float inv_r[4];
#pragma unroll
    for (int r = 0; r < 4; r++) inv_r[r] = __shfl(inv, g4 + r);
    const long obase = ((long)(b * SEQ + qhi * 64 + wid * 16 + g4)) * (NH * HD) + (long)h * HD;
#pragma unroll
    for (int r = 0; r < 4; r++)
#pragma unroll
      for (int dt = 0; dt < 8; dt++)
        attn_out[obase + (long)r * (NH * HD) + dt * 16 + l15] = f2bf(accH[dt][r] * inv_r[r]);
  }
  {
    float inv = 1.f / lL;
    float inv_r[4];
#pragma unroll
    for (int r = 0; r < 4; r++) inv_r[r] = __shfl(inv, g4 + r);
    const long obase = ((long)(b * SEQ + qlo * 64 + wid * 16 + g4)) * (NH * HD) + (long)h * HD;
#pragma unroll
    for (int r = 0; r < 4; r++)
#pragma unroll
      for (int dt = 0; dt < 8; dt++)
        attn_out[obase + (long)r * (NH * HD) + dt * 16 + l15] = f2bf(accL[dt][r] * inv_r[r]);
  }
}

// ---------------- launch ----------------
extern "C" void kernel_launch(void* const* d_in, const int* in_sizes, int n_in,
                              void* d_out, int out_size, void* d_ws, size_t ws_size,
                              hipStream_t stream) {
  const float* x = (const float*)d_in[0];
  const float* Wq = (const float*)d_in[1];
  const float* Wk = (const float*)d_in[2];
  const float* Wv = (const float*)d_in[3];
  const float* Wo = (const float*)d_in[4];

  char* w = (char*)d_ws;
  float* ropetab = (float*)w;  w += (size_t)SEQ * HD * 4;
  short* xb  = (short*)w;  w += (size_t)MTOT * DIM * 2;
  short* WqT = (short*)w;  w += (size_t)DIM * DIM * 2;
  short* WkT = (short*)w;  w += (size_t)(KVH * HD) * DIM * 2;
  short* WvT = (short*)w;  w += (size_t)(KVH * HD) * DIM * 2;
  short* WoT = (short*)w;  w += (size_t)DIM * DIM * 2;
  short* q_r = (short*)w;  w += (size_t)BATCH * NH * SEQ * HD * 2;
  short* k_r = (short*)w;  w += (size_t)BATCH * KVH * SEQ * HD * 2;
  short* v_r = (short*)w;  w += (size_t)BATCH * KVH * SEQ * HD * 2;
  short* attn = (short*)w; w += (size_t)MTOT * DIM * 2;
  // v_t aliases xb: xb's last reader is k_gemm_kv, which precedes k_transpose_v in-stream.
  short* v_t = xb;

  k_rope_table<<<SEQ, 64, 0, stream>>>(ropetab);
  k_cvt_bf16<<<(MTOT * DIM / 4 + 255) / 256, 256, 0, stream>>>(x, xb, MTOT * DIM / 4);
  k_transpose<<<dim3(DIM / 32, DIM / 32), 256, 0, stream>>>(Wq, WqT, DIM, DIM);
  k_transpose<<<dim3((KVH * HD) / 32, DIM / 32), 256, 0, stream>>>(Wk, WkT, DIM, KVH * HD);
  k_transpose<<<dim3((KVH * HD) / 32, DIM / 32), 256, 0, stream>>>(Wv, WvT, DIM, KVH * HD);
  k_transpose<<<dim3(DIM / 32, DIM / 32), 256, 0, stream>>>(Wo, WoT, DIM, DIM);

  k_gemm_q<<<dim3(DIM / 128, MTOT / 128), 256, 0, stream>>>(xb, WqT, q_r, MTOT, DIM, DIM);
  k_gemm_kv<<<dim3((KVH * HD) / 128, MTOT / 128, 2), 256, 0, stream>>>(xb, WkT, WvT, k_r, v_r,
                                                                       MTOT, KVH * HD, DIM);
  k_transpose_v<<<dim3(SEQ / 64, HD / 64, BATCH * KVH), 256, 0, stream>>>(v_r, v_t);
  k_rope<<<(BATCH * NH * SEQ * 64 + 255) / 256, 256, 0, stream>>>(q_r, ropetab, BATCH * NH * SEQ * 64, SCALE_L2E);
  k_rope<<<(BATCH * KVH * SEQ * 64 + 255) / 256, 256, 0, stream>>>(k_r, ropetab, BATCH * KVH * SEQ * 64, 1.0f);

  k_attn<<<dim3(SEQ / 128, BATCH * NH), 256, 0, stream>>>(q_r, k_r, v_t, attn);
  k_gemm_o<<<dim3(DIM / 128, MTOT / 128), 256, 0, stream>>>(attn, WoT, (float*)d_out, MTOT, DIM, DIM);
}

// Round 9
// 327.033 us; speedup vs baseline: 2.7719x; 1.1048x over previous
//
#include <hip/hip_runtime.h>
#include <hip/hip_bf16.h>

#define DIM 2048
#define NH 16
#define KVH 4
#define HD 128
#define BATCH 2
#define SEQ 2048
#define MTOT (BATCH*SEQ)
#define NQKV (NH*HD + 2*KVH*HD)   // 3072
#define SCALE 0.08838834764831845f
// SCALE * log2(e): QK^T scores land in log2 units -> exp2f softmax
#define SCALE_L2E 0.12751743762f

using f32x4 = __attribute__((ext_vector_type(4))) float;
using s16x4 = __attribute__((ext_vector_type(4))) short;
using s16x8 = __attribute__((ext_vector_type(8))) short;
using bf16x8 = __attribute__((ext_vector_type(8))) __bf16;

__device__ inline short f2bf(float x) { __bf16 h = (__bf16)x; return __builtin_bit_cast(short, h); }
__device__ inline float bf2f(short s) { return (float)__builtin_bit_cast(__bf16, s); }

// Contiguous 8-elem fragment (single ds_read_b128). Enumeration k=(l>>4)*8+j;
// valid when BOTH mfma operands use it (intra-K enumeration cancels).
__device__ inline bf16x8 ld_frag128(const short* p) {
  return __builtin_bit_cast(bf16x8, *(const s16x8*)p);
}

// Split 4+4 fragment at p / p+16 (two ds_read_b64). slot j<4 -> k=(l>>4)*4+j,
// j>=4 -> k=16+(l>>4)*4+(j-4). Matches pack_p(s) so exp'd S regs ARE P.
__device__ inline bf16x8 ld_frag(const short* p) {
  s16x4 lo = *(const s16x4*)p;
  s16x4 hi = *(const s16x4*)(p + 16);
  s16x8 f = __builtin_shufflevector(lo, hi, 0, 1, 2, 3, 4, 5, 6, 7);
  return __builtin_bit_cast(bf16x8, f);
}

__device__ inline bf16x8 pack_p(f32x4 a, f32x4 b) {
  bf16x8 o;
  o[0] = (__bf16)a[0]; o[1] = (__bf16)a[1]; o[2] = (__bf16)a[2]; o[3] = (__bf16)a[3];
  o[4] = (__bf16)b[0]; o[5] = (__bf16)b[1]; o[6] = (__bf16)b[2]; o[7] = (__bf16)b[3];
  return o;
}

// ---------------- prep kernels ----------------

__global__ void k_rope_table(float* __restrict__ tab) {
  int n = blockIdx.x, i = threadIdx.x;  // i in [0,64)
  float inv = expf(-(2.f * i / (float)HD) * logf(10000.f));
  float a = (float)n * inv;
  tab[n * HD + i] = cosf(a);
  tab[n * HD + 64 + i] = sinf(a);
}

__global__ void k_cvt_bf16(const float* __restrict__ in, short* __restrict__ out, int n4) {
  int i = blockIdx.x * 256 + threadIdx.x;
  if (i >= n4) return;
  f32x4 v = *(const f32x4*)(in + (size_t)i * 4);
  s16x4 o;
  o[0] = f2bf(v[0]); o[1] = f2bf(v[1]); o[2] = f2bf(v[2]); o[3] = f2bf(v[3]);
  *(s16x4*)(out + (size_t)i * 4) = o;
}

// W f32 [K][N] -> WT bf16 [N][K]
__global__ __launch_bounds__(256) void k_transpose(const float* __restrict__ W, short* __restrict__ WT,
                                                   int K, int N) {
  __shared__ float t[32][33];
  int n0 = blockIdx.x * 32, k0 = blockIdx.y * 32;
  int tx = threadIdx.x & 31, ty = threadIdx.x >> 5;
#pragma unroll
  for (int i = 0; i < 4; i++) t[ty + i * 8][tx] = W[(size_t)(k0 + ty + i * 8) * N + n0 + tx];
  __syncthreads();
#pragma unroll
  for (int i = 0; i < 4; i++) WT[(size_t)(n0 + ty + i * 8) * K + k0 + tx] = f2bf(t[tx][ty + i * 8]);
}

// V bf16 [.][SEQ][HD] -> [.][HD][SEQ], 64x64 tiles
__global__ __launch_bounds__(256) void k_transpose_v(const short* __restrict__ v_r, short* __restrict__ v_t) {
  __shared__ short t[64][70];
  const int z = blockIdx.z;
  const int s0 = blockIdx.x * 64, d0 = blockIdx.y * 64;
  const long ibase = ((long)z * SEQ + s0) * HD + d0;
  const long obase = ((long)z * HD + d0) * SEQ + s0;
  const int tid = threadIdx.x;
#pragma unroll
  for (int c = 0; c < 4; c++) {
    int chunk = tid + c * 256;              // 0..1023
    int row = chunk >> 4, col4 = (chunk & 15) * 4;
    *(s16x4*)&t[row][col4] = *(const s16x4*)(v_r + ibase + (long)row * HD + col4);
  }
  __syncthreads();
#pragma unroll
  for (int c = 0; c < 4; c++) {
    int chunk = tid + c * 256;
    int row = chunk >> 4, col4 = (chunk & 15) * 4; // row: hd idx, col4: seq chunk
    s16x4 o;
    o[0] = t[col4 + 0][row]; o[1] = t[col4 + 1][row];
    o[2] = t[col4 + 2][row]; o[3] = t[col4 + 3][row];
    *(s16x4*)(v_t + obase + (long)row * SEQ + col4) = o;
  }
}

// ---------------- GEMM core: C = A @ BT^T (128x128 tile, BK=32, b128 frags,
// T3-minimum 2-phase LDS double-buffer: one barrier per K-step) ----------------
template <class Epi>
__device__ inline void gemm_core(const short* __restrict__ A, const short* __restrict__ BT,
                                 int K, Epi epi) {
  __shared__ short As[2][128 * 32];
  __shared__ short Bs[2][128 * 32];
  const int tid = threadIdx.x;
  const int wid = tid >> 6, lane = tid & 63;
  const int m0 = blockIdx.y * 128, n0 = blockIdx.x * 128;
  const int wr = wid >> 1, wc = wid & 1;
  const int l15 = lane & 15, g4 = (lane >> 4) * 4, kg8 = (lane >> 4) * 8;
  const int lrow = lane >> 2;         // 0..15
  const int lcol = (lane & 3) * 8;    // 0,8,16,24
  f32x4 acc[4][4] = {};

  const long abase = (long)(m0 + lrow) * K + lcol;
  const long bbase = (long)(n0 + lrow) * K + lcol;

  auto stage = [&](int buf, int kt) {
#pragma unroll
    for (int i = 0; i < 2; i++) {
      int r0 = wid * 32 + i * 16;
      const short* gp = A + abase + (long)r0 * K + kt;
      __builtin_amdgcn_global_load_lds((const __attribute__((address_space(1))) void*)gp,
                                       (__attribute__((address_space(3))) void*)&As[buf][r0 * 32], 16, 0, 0);
      const short* gq = BT + bbase + (long)r0 * K + kt;
      __builtin_amdgcn_global_load_lds((const __attribute__((address_space(1))) void*)gq,
                                       (__attribute__((address_space(3))) void*)&Bs[buf][r0 * 32], 16, 0, 0);
    }
  };
  auto compute = [&](int buf) {
    bf16x8 av[4];
#pragma unroll
    for (int mt = 0; mt < 4; mt++) av[mt] = ld_frag128(&As[buf][(wr * 64 + mt * 16 + l15) * 32 + kg8]);
#pragma unroll
    for (int nt = 0; nt < 4; nt++) {
      bf16x8 bv = ld_frag128(&Bs[buf][(wc * 64 + nt * 16 + l15) * 32 + kg8]);
#pragma unroll
      for (int mt = 0; mt < 4; mt++)
        acc[mt][nt] = __builtin_amdgcn_mfma_f32_16x16x32_bf16(av[mt], bv, acc[mt][nt], 0, 0, 0);
    }
  };

  const int nk = K >> 5;  // even (K=2048 -> 64)
  stage(0, 0);
  __syncthreads();        // implicit vmcnt(0) drains prologue stage
  for (int t = 0; t < nk; t += 2) {
    if (t + 1 < nk) stage(1, (t + 1) << 5);   // next tile under current compute
    compute(0);
    __syncthreads();                           // drains stage(1), guards As[0] reuse
    if (t + 2 < nk) stage(0, (t + 2) << 5);
    compute(1);
    __syncthreads();
  }

#pragma unroll
  for (int mt = 0; mt < 4; mt++)
#pragma unroll
    for (int nt = 0; nt < 4; nt++) {
      int row = m0 + wr * 64 + mt * 16 + g4;
      int col = n0 + wc * 64 + nt * 16 + l15;
#pragma unroll
      for (int r = 0; r < 4; r++) epi(row + r, col, acc[mt][nt][r]);
    }
}

// Fused QKV projection: BT = [WqT | WkT | WvT] (3072 x K), outputs routed by col.
__global__ __launch_bounds__(256) void k_gemm_qkv(const short* __restrict__ A, const short* __restrict__ BT,
                                                  short* __restrict__ q_r, short* __restrict__ k_r,
                                                  short* __restrict__ v_r, int K) {
  gemm_core(A, BT, K, [=](int row, int col, float v) {
    int b = row >> 11, n = row & (SEQ - 1);
    int hd = col & (HD - 1);
    short* dst; long hb;
    if (col < NH * HD) { dst = q_r; hb = b * NH + (col >> 7); }
    else if (col < NH * HD + KVH * HD) { dst = k_r; hb = b * KVH + ((col - NH * HD) >> 7); }
    else { dst = v_r; hb = b * KVH + ((col - NH * HD - KVH * HD) >> 7); }
    dst[(hb * SEQ + n) * HD + hd] = f2bf(v);
  });
}

__global__ __launch_bounds__(256) void k_gemm_o(const short* __restrict__ A, const short* __restrict__ BT,
                                                float* __restrict__ C, int N, int K) {
  gemm_core(A, BT, K, [=](int row, int col, float v) {
    C[(long)row * N + col] = v;
  });
}

// ---------------- RoPE in-place on [.][heads][SEQ][HD] bf16, optional scale fold ----------------
__global__ void k_rope(short* __restrict__ t, const float* __restrict__ tab, int total, float scale) {
  int idx = blockIdx.x * 256 + threadIdx.x;
  if (idx >= total) return;
  int i = idx & 63;
  int n = (idx >> 6) & (SEQ - 1);
  long base = (long)(idx >> 6) * HD;
  float c = tab[n * HD + i], s = tab[n * HD + 64 + i];
  float x1 = bf2f(t[base + i]), x2 = bf2f(t[base + 64 + i]);
  t[base + i] = f2bf((x1 * c - x2 * s) * scale);
  t[base + 64 + i] = f2bf((x2 * c + x1 * s) * scale);
}

// ---------------- flash attention (paired q-tiles, swapped QK^T) ----------------
// Block handles q-tiles qlo=blockIdx.x and qhi=31-blockIdx.x in ONE fused KV loop:
// constant 33 tiles of q-work per block (perfect balance), KV prefix staged once.
// q_r pre-scaled by SCALE*log2(e) -> softmax in exp2 domain.
__global__ __launch_bounds__(256, 2) void k_attn(const short* __restrict__ q_r, const short* __restrict__ k_r,
                                                 const short* __restrict__ v_t, short* __restrict__ attn_out) {
  __shared__ short Kl[64 * 136];      // [kv 64][hd 128 pad 136]
  __shared__ short Vt[128 * 68];      // [hd 128][kv 64 pad 68]
  const int tid = threadIdx.x, wid = tid >> 6, lane = tid & 63;
  const int l15 = lane & 15, g4 = (lane >> 4) * 4, kg8 = (lane >> 4) * 8;
  const int qlo = blockIdx.x;               // 0..15
  const int qhi = 31 - qlo;                 // 16..31
  const int bh = blockIdx.y;
  const int b = bh >> 4, h = bh & 15, kvh = h >> 2;

  const long hbase = ((long)(b * NH + h)) * SEQ;
  bf16x8 aqL[4], aqH[4];
#pragma unroll
  for (int kt = 0; kt < 4; kt++) {
    aqL[kt] = ld_frag128(q_r + (hbase + qlo * 64 + wid * 16 + l15) * HD + kt * 32 + kg8);
    aqH[kt] = ld_frag128(q_r + (hbase + qhi * 64 + wid * 16 + l15) * HD + kt * 32 + kg8);
  }

  f32x4 accL[8] = {}, accH[8] = {};
  float mL = -1e30f, lL = 0.f, mH = -1e30f, lH = 0.f;
  const long kvbase = ((long)(b * KVH + kvh)) * SEQ * HD;
  const long vtbase = ((long)(b * KVH + kvh)) * HD * SEQ;
  const int qgL = qlo * 64 + wid * 16 + l15;
  const int qgH = qhi * 64 + wid * 16 + l15;

  s16x8 kreg[4], vreg[4];
#pragma unroll
  for (int c = 0; c < 4; c++) {
    int chunk = tid + c * 256;
    int kr = chunk >> 4, kc = (chunk & 15) * 8;
    kreg[c] = *(const s16x8*)(k_r + kvbase + (long)kr * HD + kc);
    int vr = chunk >> 3, vc = (chunk & 7) * 8;
    vreg[c] = *(const s16x8*)(v_t + vtbase + (long)vr * SEQ + vc);
  }

  for (int t64 = 0; t64 <= qhi; t64++) {
    __syncthreads();
#pragma unroll
    for (int c = 0; c < 4; c++) {
      int chunk = tid + c * 256;
      int kr = chunk >> 4, kc = (chunk & 15) * 8;
      *(s16x8*)&Kl[kr * 136 + kc] = kreg[c];
      int vr = chunk >> 3, vc = (chunk & 7) * 8;
      *(s16x8*)&Vt[vr * 68 + vc] = vreg[c];
    }
    __syncthreads();

    if (t64 < qhi) {
      const int kv0n = (t64 + 1) * 64;
#pragma unroll
      for (int c = 0; c < 4; c++) {
        int chunk = tid + c * 256;
        int kr = chunk >> 4, kc = (chunk & 15) * 8;
        kreg[c] = *(const s16x8*)(k_r + kvbase + (long)(kv0n + kr) * HD + kc);
        int vr = chunk >> 3, vc = (chunk & 7) * 8;
        vreg[c] = *(const s16x8*)(v_t + vtbase + (long)vr * SEQ + kv0n + vc);
      }
    }

    const int kv0 = t64 * 64;
    const bool actL = (t64 <= qlo);

    // QK^T (swapped: kv in regs, q in lanes) for both tiles
    f32x4 sH[4] = {}, sL[4] = {};
#pragma unroll
    for (int nt = 0; nt < 4; nt++) {
#pragma unroll
      for (int kt = 0; kt < 4; kt++) {
        bf16x8 bk = ld_frag128(&Kl[(nt * 16 + l15) * 136 + kt * 32 + kg8]);
        sH[nt] = __builtin_amdgcn_mfma_f32_16x16x32_bf16(bk, aqH[kt], sH[nt], 0, 0, 0);
        if (actL) sL[nt] = __builtin_amdgcn_mfma_f32_16x16x32_bf16(bk, aqL[kt], sL[nt], 0, 0, 0);
      }
    }

    // causal mask (only the diagonal tile of each q-tile needs it)
    if (t64 == qhi) {
#pragma unroll
      for (int nt = 0; nt < 4; nt++) {
        int kvb = kv0 + nt * 16 + g4;
#pragma unroll
        for (int r = 0; r < 4; r++) sH[nt][r] = (kvb + r > qgH) ? -1e30f : sH[nt][r];
      }
    }
    if (actL && t64 == qlo) {
#pragma unroll
      for (int nt = 0; nt < 4; nt++) {
        int kvb = kv0 + nt * 16 + g4;
#pragma unroll
        for (int r = 0; r < 4; r++) sL[nt][r] = (kvb + r > qgL) ? -1e30f : sL[nt][r];
      }
    }

    // ---- softmax + PV for H ----
    {
      float tm = -1e30f;
#pragma unroll
      for (int nt = 0; nt < 4; nt++)
        tm = fmaxf(tm, fmaxf(fmaxf(sH[nt][0], sH[nt][1]), fmaxf(sH[nt][2], sH[nt][3])));
      tm = fmaxf(tm, __shfl_xor(tm, 16));
      tm = fmaxf(tm, __shfl_xor(tm, 32));
      if (!__all(tm - mH <= 8.f)) {          // T13 defer-rescale
        float mn = fmaxf(mH, tm);
        float corr = exp2f(mH - mn);
        mH = mn;
        lH *= corr;
        float corr_r[4];
#pragma unroll
        for (int r = 0; r < 4; r++) corr_r[r] = __shfl(corr, g4 + r);
#pragma unroll
        for (int dt = 0; dt < 8; dt++)
#pragma unroll
          for (int r = 0; r < 4; r++) accH[dt][r] *= corr_r[r];
      }
      float rs = 0.f;
#pragma unroll
      for (int nt = 0; nt < 4; nt++)
#pragma unroll
        for (int r = 0; r < 4; r++) {
          float p = exp2f(sH[nt][r] - mH);
          sH[nt][r] = p;
          rs += p;
        }
      rs += __shfl_xor(rs, 16);
      rs += __shfl_xor(rs, 32);
      lH += rs;
      bf16x8 pa0 = pack_p(sH[0], sH[1]);
      bf16x8 pa1 = pack_p(sH[2], sH[3]);
#pragma unroll
      for (int dt = 0; dt < 8; dt++) {
        bf16x8 bv0 = ld_frag(&Vt[(dt * 16 + l15) * 68 + g4]);
        accH[dt] = __builtin_amdgcn_mfma_f32_16x16x32_bf16(pa0, bv0, accH[dt], 0, 0, 0);
        bf16x8 bv1 = ld_frag(&Vt[(dt * 16 + l15) * 68 + 32 + g4]);
        accH[dt] = __builtin_amdgcn_mfma_f32_16x16x32_bf16(pa1, bv1, accH[dt], 0, 0, 0);
      }
    }

    // ---- softmax + PV for L ----
    if (actL) {
      float tm = -1e30f;
#pragma unroll
      for (int nt = 0; nt < 4; nt++)
        tm = fmaxf(tm, fmaxf(fmaxf(sL[nt][0], sL[nt][1]), fmaxf(sL[nt][2], sL[nt][3])));
      tm = fmaxf(tm, __shfl_xor(tm, 16));
      tm = fmaxf(tm, __shfl_xor(tm, 32));
      if (!__all(tm - mL <= 8.f)) {
        float mn = fmaxf(mL, tm);
        float corr = exp2f(mL - mn);
        mL = mn;
        lL *= corr;
        float corr_r[4];
#pragma unroll
        for (int r = 0; r < 4; r++) corr_r[r] = __shfl(corr, g4 + r);
#pragma unroll
        for (int dt = 0; dt < 8; dt++)
#pragma unroll
          for (int r = 0; r < 4; r++) accL[dt][r] *= corr_r[r];
      }
      float rs = 0.f;
#pragma unroll
      for (int nt = 0; nt < 4; nt++)
#pragma unroll
        for (int r = 0; r < 4; r++) {
          float p = exp2f(sL[nt][r] - mL);
          sL[nt][r] = p;
          rs += p;
        }
      rs += __shfl_xor(rs, 16);
      rs += __shfl_xor(rs, 32);
      lL += rs;
      bf16x8 pa0 = pack_p(sL[0], sL[1]);
      bf16x8 pa1 = pack_p(sL[2], sL[3]);
#pragma unroll
      for (int dt = 0; dt < 8; dt++) {
        bf16x8 bv0 = ld_frag(&Vt[(dt * 16 + l15) * 68 + g4]);
        accL[dt] = __builtin_amdgcn_mfma_f32_16x16x32_bf16(pa0, bv0, accL[dt], 0, 0, 0);
        bf16x8 bv1 = ld_frag(&Vt[(dt * 16 + l15) * 68 + 32 + g4]);
        accL[dt] = __builtin_amdgcn_mfma_f32_16x16x32_bf16(pa1, bv1, accL[dt], 0, 0, 0);
      }
    }
  }

  // epilogue: both tiles
  {
    float inv = 1.f / lH;
    float inv_r[4];
#pragma unroll
    for (int r = 0; r < 4; r++) inv_r[r] = __shfl(inv, g4 + r);
    const long obase = ((long)(b * SEQ + qhi * 64 + wid * 16 + g4)) * (NH * HD) + (long)h * HD;
#pragma unroll
    for (int r = 0; r < 4; r++)
#pragma unroll
      for (int dt = 0; dt < 8; dt++)
        attn_out[obase + (long)r * (NH * HD) + dt * 16 + l15] = f2bf(accH[dt][r] * inv_r[r]);
  }
  {
    float inv = 1.f / lL;
    float inv_r[4];
#pragma unroll
    for (int r = 0; r < 4; r++) inv_r[r] = __shfl(inv, g4 + r);
    const long obase = ((long)(b * SEQ + qlo * 64 + wid * 16 + g4)) * (NH * HD) + (long)h * HD;
#pragma unroll
    for (int r = 0; r < 4; r++)
#pragma unroll
      for (int dt = 0; dt < 8; dt++)
        attn_out[obase + (long)r * (NH * HD) + dt * 16 + l15] = f2bf(accL[dt][r] * inv_r[r]);
  }
}

// ---------------- launch ----------------
extern "C" void kernel_launch(void* const* d_in, const int* in_sizes, int n_in,
                              void* d_out, int out_size, void* d_ws, size_t ws_size,
                              hipStream_t stream) {
  const float* x = (const float*)d_in[0];
  const float* Wq = (const float*)d_in[1];
  const float* Wk = (const float*)d_in[2];
  const float* Wv = (const float*)d_in[3];
  const float* Wo = (const float*)d_in[4];

  char* w = (char*)d_ws;
  float* ropetab = (float*)w;  w += (size_t)SEQ * HD * 4;
  short* xb  = (short*)w;  w += (size_t)MTOT * DIM * 2;
  short* WqT = (short*)w;  w += (size_t)DIM * DIM * 2;          // rows 0..2047 of concat
  short* WkT = (short*)w;  w += (size_t)(KVH * HD) * DIM * 2;   // rows 2048..2559
  short* WvT = (short*)w;  w += (size_t)(KVH * HD) * DIM * 2;   // rows 2560..3071
  short* WoT = (short*)w;  w += (size_t)DIM * DIM * 2;
  short* q_r = (short*)w;  w += (size_t)BATCH * NH * SEQ * HD * 2;
  short* k_r = (short*)w;  w += (size_t)BATCH * KVH * SEQ * HD * 2;
  short* v_r = (short*)w;  w += (size_t)BATCH * KVH * SEQ * HD * 2;
  short* attn = (short*)w; w += (size_t)MTOT * DIM * 2;
  // v_t aliases xb: xb's last reader is k_gemm_qkv, which precedes k_transpose_v in-stream.
  short* v_t = xb;

  k_rope_table<<<SEQ, 64, 0, stream>>>(ropetab);
  k_cvt_bf16<<<(MTOT * DIM / 4 + 255) / 256, 256, 0, stream>>>(x, xb, MTOT * DIM / 4);
  k_transpose<<<dim3(DIM / 32, DIM / 32), 256, 0, stream>>>(Wq, WqT, DIM, DIM);
  k_transpose<<<dim3((KVH * HD) / 32, DIM / 32), 256, 0, stream>>>(Wk, WkT, DIM, KVH * HD);
  k_transpose<<<dim3((KVH * HD) / 32, DIM / 32), 256, 0, stream>>>(Wv, WvT, DIM, KVH * HD);
  k_transpose<<<dim3(DIM / 32, DIM / 32), 256, 0, stream>>>(Wo, WoT, DIM, DIM);

  // Fused QKV projection: BT concat starts at WqT (WqT/WkT/WvT contiguous in ws).
  k_gemm_qkv<<<dim3(NQKV / 128, MTOT / 128), 256, 0, stream>>>(xb, WqT, q_r, k_r, v_r, DIM);
  k_transpose_v<<<dim3(SEQ / 64, HD / 64, BATCH * KVH), 256, 0, stream>>>(v_r, v_t);
  k_rope<<<(BATCH * NH * SEQ * 64 + 255) / 256, 256, 0, stream>>>(q_r, ropetab, BATCH * NH * SEQ * 64, SCALE_L2E);
  k_rope<<<(BATCH * KVH * SEQ * 64 + 255) / 256, 256, 0, stream>>>(k_r, ropetab, BATCH * KVH * SEQ * 64, 1.0f);

  k_attn<<<dim3(SEQ / 128, BATCH * NH), 256, 0, stream>>>(q_r, k_r, v_t, attn);
  k_gemm_o<<<dim3(DIM / 128, MTOT / 128), 256, 0, stream>>>(attn, WoT, (float*)d_out, DIM, DIM);
}